// Round 4
// baseline (12.193 us; speedup 1.0000x reference)
//
#include <hip/hip_runtime.h>

#define HH 256
#define WW 256
#define SS 15
#define NB 64

// Single-instruction transcendentals (v_log_f32 = log2, v_exp_f32 = exp2).
__device__ __forceinline__ float alog2(float x) {
    float r; asm("v_log_f32 %0, %1" : "=v"(r) : "v"(x)); return r;
}
__device__ __forceinline__ float aexp2(float x) {
    float r; asm("v_exp_f32 %0, %1" : "=v"(r) : "v"(x)); return r;
}
__device__ __forceinline__ float bcast(float v, int lane) {
    return __uint_as_float(__builtin_amdgcn_readlane(__float_as_uint(v), lane));
}

// Wave-independent layout, no LDS, no barrier:
//   grid = 64 batches x 32 blocks, block = 256 thr = 4 waves.
//   Each wave owns 512 contiguous output px = 2 full columns (x-major
//   flatten: out[b][i][j] is position (y=j, x=i)).
//   Lane l covers y = 4l..4l+3 of column A (px base+4l) and the same y of
//   column B (px base+256+4l)  -> dy^2 shared between columns.
// Sample points: lanes 0..14 evaluate the cubic Bernstein basis, then
// v_readlane broadcasts all 15 (sx,sy) into SGPRs (no LDS round-trip).
// Culling (exact): canvas=0 whenever d>=w, and per-column dx is uniform,
// so a sample with dx^2>=w^2 contributes nothing -> execz-skipped branch.
// Epilogue: (sqrt(m)/w+eps)^af -> exp2(0.5*af*log2(m) - af*log2(w));
// m=1e30 stays finite (exp2(~124)) and clamps to 0 like the reference.
__global__ __launch_bounds__(256) void CurveGraphic2d_kernel(
    const float* __restrict__ inputs,   // [64,4,2] normalized (y,x)
    const float* __restrict__ widths,   // [64]
    const float* __restrict__ aaf,      // [64]
    float* __restrict__ out)            // [64,256,256]
{
    const int b    = blockIdx.x >> 5;              // 32 blocks per batch
    const int blk  = blockIdx.x & 31;
    const int tid  = threadIdx.x;
    const int lane = tid & 63;
    const int r    = blk * 4 + (tid >> 6);         // region id: 0..127 per batch

    // --- per-wave sample-point setup (lanes 0..14), broadcast to SGPRs ---
    const float* kp = inputs + b * 8;              // uniform addr -> s_load
    float t  = (float)lane * (1.0f / (float)(SS - 1));
    float u  = 1.0f - t;
    float b0 = u * u * u;
    float b1 = 3.0f * t * u * u;
    float b2 = 3.0f * t * t * u;
    float b3 = t * t * t;
    float spyv = 256.0f * (b0 * kp[0] + b1 * kp[2] + b2 * kp[4] + b3 * kp[6]);
    float spxv = 256.0f * (b0 * kp[1] + b1 * kp[3] + b2 * kp[5] + b3 * kp[7]);

    float sx[SS], sy[SS];
    #pragma unroll
    for (int s = 0; s < SS; ++s) {
        sx[s] = bcast(spxv, s);                    // SGPR-resident
        sy[s] = bcast(spyv, s);
    }

    const float w  = widths[b];
    const float w2 = w * w;

    const float xA = (float)(r * 2);               // column A x
    const float xB = xA + 1.0f;                    // column B x
    const float y0 = (float)(lane * 4);

    float mA0 = 1e30f, mA1 = 1e30f, mA2 = 1e30f, mA3 = 1e30f;
    float mB0 = 1e30f, mB1 = 1e30f, mB2 = 1e30f, mB3 = 1e30f;

    #pragma unroll
    for (int s = 0; s < SS; ++s) {
        float dxA  = xA - sx[s];
        float dxxA = dxA * dxA;
        float dxB  = xB - sx[s];
        float dxxB = dxB * dxB;
        bool aA = dxxA < w2;                       // wave-uniform in practice
        bool aB = dxxB < w2;
        if (aA || aB) {
            float sys = sy[s];
            float dy0 = y0          - sys;
            float dy1 = (y0 + 1.0f) - sys;
            float dy2 = (y0 + 2.0f) - sys;
            float dy3 = (y0 + 3.0f) - sys;
            float q0 = dy0 * dy0, q1 = dy1 * dy1, q2 = dy2 * dy2, q3 = dy3 * dy3;
            if (aA) {
                mA0 = fminf(mA0, q0 + dxxA);
                mA1 = fminf(mA1, q1 + dxxA);
                mA2 = fminf(mA2, q2 + dxxA);
                mA3 = fminf(mA3, q3 + dxxA);
            }
            if (aB) {
                mB0 = fminf(mB0, q0 + dxxB);
                mB1 = fminf(mB1, q1 + dxxB);
                mB2 = fminf(mB2, q2 + dxxB);
                mB3 = fminf(mB3, q3 + dxxB);
            }
        }
    }

    const float af    = aaf[b];
    const float haf   = 0.5f * af;                 // sqrt folded into the log
    const float cbias = -af * log2f(w);

    float* dst = out + (size_t)b * (HH * WW) + r * 512 + lane * 4;

    float4 o;
    float p;
    p   = aexp2(fmaf(haf, alog2(mA0), cbias));
    o.x = fminf(fmaxf(1.0f - p, 0.0f), 1.0f);
    p   = aexp2(fmaf(haf, alog2(mA1), cbias));
    o.y = fminf(fmaxf(1.0f - p, 0.0f), 1.0f);
    p   = aexp2(fmaf(haf, alog2(mA2), cbias));
    o.z = fminf(fmaxf(1.0f - p, 0.0f), 1.0f);
    p   = aexp2(fmaf(haf, alog2(mA3), cbias));
    o.w = fminf(fmaxf(1.0f - p, 0.0f), 1.0f);
    *reinterpret_cast<float4*>(dst) = o;

    p   = aexp2(fmaf(haf, alog2(mB0), cbias));
    o.x = fminf(fmaxf(1.0f - p, 0.0f), 1.0f);
    p   = aexp2(fmaf(haf, alog2(mB1), cbias));
    o.y = fminf(fmaxf(1.0f - p, 0.0f), 1.0f);
    p   = aexp2(fmaf(haf, alog2(mB2), cbias));
    o.z = fminf(fmaxf(1.0f - p, 0.0f), 1.0f);
    p   = aexp2(fmaf(haf, alog2(mB3), cbias));
    o.w = fminf(fmaxf(1.0f - p, 0.0f), 1.0f);
    *reinterpret_cast<float4*>(dst + 256) = o;
}

extern "C" void kernel_launch(void* const* d_in, const int* in_sizes, int n_in,
                              void* d_out, int out_size, void* d_ws, size_t ws_size,
                              hipStream_t stream) {
    const float* inputs = (const float*)d_in[0];
    const float* widths = (const float*)d_in[1];
    const float* aaf    = (const float*)d_in[2];
    float* out = (float*)d_out;

    const int blocks = NB * 32;                    // 2048 blocks, 8192 waves
    CurveGraphic2d_kernel<<<blocks, 256, 0, stream>>>(inputs, widths, aaf, out);
}